// Round 1
// baseline (119.255 us; speedup 1.0000x reference)
//
#include <hip/hip_runtime.h>

#define Bb 64
#define Ll 32
#define Hh 128
#define Oo 16384
#define Cc 32
#define TO 16

// ---------------------------------------------------------------------------
// prep: A[b,h] = (relu(z@Wz+bz) @ W1[:H]) [no b1 -- folded into G]
// grid 32 blocks x 256 threads; each block handles 2 rows of b.
// ---------------------------------------------------------------------------
__global__ __launch_bounds__(256) void prep_kernel(
    const float* __restrict__ z, const float* __restrict__ Wz,
    const float* __restrict__ bz, const float* __restrict__ W1,
    float* __restrict__ A)
{
    __shared__ float pz[2][Hh];
    const int t  = threadIdx.x;
    const int h  = t & (Hh - 1);
    const int bb = t >> 7;                 // 0..1
    const int b  = blockIdx.x * 2 + bb;

    float v = bz[h];
#pragma unroll
    for (int c = 0; c < Ll; ++c)
        v = fmaf(z[b * Ll + c], Wz[c * Hh + h], v);
    pz[bb][h] = fmaxf(v, 0.f);
    __syncthreads();

    float a = 0.f;
#pragma unroll
    for (int k = 0; k < Hh; ++k)
        a = fmaf(pz[bb][k], W1[k * Hh + h], a);
    A[b * Hh + h] = a;
}

// ---------------------------------------------------------------------------
// main: out[b,o] = SA2[b] + SG2[o] + sum_h 0.5*W2[h]*|A[b,h]+G[o,h]| + b2
//   (uses w*relu(x) = 0.5*w*x + 0.5*w*|x|)
// grid O/TO = 1024 blocks x 256 threads (4 waves). lane = b (B==64==wave).
// Each block: build G-tile (TO x 128) in LDS from fe, then each wave handles
// 4 o-columns with A row in registers.
// ---------------------------------------------------------------------------
__global__ __launch_bounds__(256) void main_kernel(
    const float* __restrict__ A,  const float* __restrict__ fe,
    const float* __restrict__ fb, const float* __restrict__ W1,
    const float* __restrict__ b1, const float* __restrict__ W2,
    const float* __restrict__ b2, float* __restrict__ out)
{
    __shared__ float fe_s[TO][Cc];   // 2 KB
    __shared__ float g_s[TO][Hh];    // 8 KB
    __shared__ float w2h_s[Hh];      // 0.5*W2
    __shared__ float fb_s[TO];

    const int t  = threadIdx.x;
    const int o0 = blockIdx.x * TO;
    const int h  = t & (Hh - 1);
    const int og = t >> 7;           // 0..1

    // --- stage small inputs ---
    if (t < TO * Cc / 4)             // 128 threads, 16B each
        ((float4*)fe_s)[t] = ((const float4*)(fe + o0 * Cc))[t];
    if (t < Hh) w2h_s[t] = 0.5f * W2[t];
    if (t < TO) fb_s[t] = fb[o0 + t];

    // W1_f column h into registers (coalesced, L2-hot)
    float w1f[Cc];
#pragma unroll
    for (int c = 0; c < Cc; ++c)
        w1f[c] = W1[(Hh + c) * Hh + h];
    const float w1b = W1[(Hh + Cc) * Hh + h];
    const float b1h = b1[h];

    __syncthreads();

    // --- G phase: 8 o per thread ---
#pragma unroll
    for (int j = 0; j < 8; ++j) {
        const int o = og * 8 + j;
        float g = fmaf(fb_s[o], w1b, b1h);
#pragma unroll
        for (int cc = 0; cc < Cc / 4; ++cc) {
            const float4 f4 = ((const float4*)fe_s[o])[cc];
            g = fmaf(f4.x, w1f[4 * cc + 0], g);
            g = fmaf(f4.y, w1f[4 * cc + 1], g);
            g = fmaf(f4.z, w1f[4 * cc + 2], g);
            g = fmaf(f4.w, w1f[4 * cc + 3], g);
        }
        g_s[o][h] = g;
    }
    __syncthreads();

    // --- lane = b ---
    const int lane = t & 63;
    const int wave = t >> 6;

    // A row -> 128 registers
    float4 a4[Hh / 4];
#pragma unroll
    for (int j = 0; j < Hh / 4; ++j)
        a4[j] = ((const float4*)(A + lane * Hh))[j];

    // SA2 = sum_h 0.5*W2[h]*A[b,h]
    float sa2 = 0.f;
#pragma unroll
    for (int j = 0; j < Hh / 4; ++j) {
        const float4 w4 = ((const float4*)w2h_s)[j];
        sa2 += w4.x * a4[j].x + w4.y * a4[j].y + w4.z * a4[j].z + w4.w * a4[j].w;
    }

    const float w2l0 = w2h_s[lane];
    const float w2l1 = w2h_s[lane + 64];
    const float b2v  = b2[0];

    // SG2 per o via lane-split + butterfly reduce
    float acc[4];
#pragma unroll
    for (int k = 0; k < 4; ++k) {
        const int o = wave * 4 + k;
        float p = w2l0 * g_s[o][lane] + w2l1 * g_s[o][lane + 64];
#pragma unroll
        for (int m = 32; m >= 1; m >>= 1)
            p += __shfl_xor(p, m, 64);
        acc[k] = sa2 + p + b2v;
    }

    // --- inner loop: acc[k] += 0.5*W2[h]*|A[b,h] + G[o_k,h]| ---
#pragma unroll
    for (int j = 0; j < Hh / 4; ++j) {
        const float4 w4 = ((const float4*)w2h_s)[j];
#pragma unroll
        for (int k = 0; k < 4; ++k) {
            const int o = wave * 4 + k;
            const float4 g4 = ((const float4*)(g_s[o]))[j];
            const float t0 = a4[j].x + g4.x;
            const float t1 = a4[j].y + g4.y;
            const float t2 = a4[j].z + g4.z;
            const float t3 = a4[j].w + g4.w;
            acc[k] = fmaf(__builtin_fabsf(t0), w4.x, acc[k]);
            acc[k] = fmaf(__builtin_fabsf(t1), w4.y, acc[k]);
            acc[k] = fmaf(__builtin_fabsf(t2), w4.z, acc[k]);
            acc[k] = fmaf(__builtin_fabsf(t3), w4.w, acc[k]);
        }
    }

#pragma unroll
    for (int k = 0; k < 4; ++k)
        out[lane * Oo + o0 + wave * 4 + k] = acc[k];
}

extern "C" void kernel_launch(void* const* d_in, const int* in_sizes, int n_in,
                              void* d_out, int out_size, void* d_ws, size_t ws_size,
                              hipStream_t stream) {
    (void)in_sizes; (void)n_in; (void)out_size; (void)ws_size;
    const float* z   = (const float*)d_in[0];   // (64,32)
    const float* fe  = (const float*)d_in[1];   // (16384,32)
    const float* fb  = (const float*)d_in[2];   // (16384,1)
    const float* Wz  = (const float*)d_in[3];   // (32,128)
    const float* bz  = (const float*)d_in[4];   // (128,)
    const float* W1  = (const float*)d_in[5];   // (161,128)
    const float* b1  = (const float*)d_in[6];   // (128,)
    const float* W2  = (const float*)d_in[7];   // (128,1)
    const float* b2  = (const float*)d_in[8];   // (1,)
    float* out = (float*)d_out;                 // (64,16384)
    float* A   = (float*)d_ws;                  // 64*128 floats

    prep_kernel<<<Bb / 2, 256, 0, stream>>>(z, Wz, bz, W1, A);
    main_kernel<<<Oo / TO, 256, 0, stream>>>(A, fe, fb, W1, b1, W2, b2, out);
}